// Round 12
// baseline (357.527 us; speedup 1.0000x reference)
//
#include <hip/hip_runtime.h>

#define N_NODES 100000
#define N_EDGES 1600000
#define D_IN 128
#define D_HID 64
#define BN_EPS 1e-5f

#define BUCKET_SHIFT 6
#define BUCKET_W 64                                     // nodes per bucket
#define N_BUCKETS ((N_NODES + BUCKET_W - 1) / BUCKET_W) // 1563
#define SCAN_CHUNKS ((N_BUCKETS + 1023) / 1024)         // 2
#define N_BIN_BLOCKS 1000
#define EDGES_PER_BLOCK (N_EDGES / N_BIN_BLOCKS)        // 1600 exact
#define GT 5                                            // gemm tiles per block

typedef __attribute__((ext_vector_type(8))) short bf16x8;
typedef __attribute__((ext_vector_type(4))) float f32x4;
typedef __attribute__((ext_vector_type(8))) _Float16 f16x8;
typedef __attribute__((ext_vector_type(4))) int int4v;

__device__ __forceinline__ ushort f2bf(float f) {       // RTNE fp32 -> bf16
    unsigned u = __float_as_uint(f);
    u += 0x7FFF + ((u >> 16) & 1);
    return (ushort)(u >> 16);
}

// --- 1. per-bucket edge counts; persist per-block histograms ---
__global__ __launch_bounds__(256) void bin_count_kernel(const int* __restrict__ col,
                                                        int* __restrict__ bcount,
                                                        int* __restrict__ bhist) {
    __shared__ int hist[N_BUCKETS];
    const int t = threadIdx.x;
    for (int i = t; i < N_BUCKETS; i += 256) hist[i] = 0;
    __syncthreads();
    const int e0 = blockIdx.x * EDGES_PER_BLOCK;
    for (int j = t; j < EDGES_PER_BLOCK; j += 256)
        atomicAdd(&hist[col[e0 + j] >> BUCKET_SHIFT], 1);
    __syncthreads();
    for (int i = t; i < N_BUCKETS; i += 256) {
        int h = hist[i];
        bhist[blockIdx.x * N_BUCKETS + i] = h;
        if (h) atomicAdd(&bcount[i], h);
    }
}

// --- 2. exclusive scan of bucket counts (single block, 2 chunks of 1024) ---
__global__ __launch_bounds__(1024) void scan_buckets_kernel(const int* __restrict__ bcount,
                                                            int* __restrict__ bstart,
                                                            int* __restrict__ bcursor,
                                                            int* __restrict__ row_start) {
    __shared__ int tmp[1024];
    __shared__ int base_s;
    const int t = threadIdx.x;
    if (t == 0) base_s = 0;
    __syncthreads();
    for (int c = 0; c < SCAN_CHUNKS; ++c) {
        const int i = c * 1024 + t;
        int val = (i < N_BUCKETS) ? bcount[i] : 0;
        tmp[t] = val;
        for (int off = 1; off < 1024; off <<= 1) {
            __syncthreads();
            int add = (t >= off) ? tmp[t - off] : 0;
            __syncthreads();
            tmp[t] += add;
        }
        __syncthreads();
        int incl = tmp[t] + base_s;
        int excl = incl - val;
        if (i < N_BUCKETS) {
            bstart[i] = excl;
            bcursor[i] = excl;
        }
        if (i == N_BUCKETS - 1) {
            bstart[N_BUCKETS] = incl;
            row_start[N_NODES] = incl;   // CSR sentinel
        }
        __syncthreads();
        if (t == 1023) base_s += tmp[t];
        __syncthreads();
    }
}

// --- 3. scatter edges into bucket-grouped array, packed (cl<<17)|row ---
__global__ __launch_bounds__(256) void bin_scatter_kernel(const int* __restrict__ row,
                                                          const int* __restrict__ col,
                                                          const int* __restrict__ bhist,
                                                          int* __restrict__ bcursor,
                                                          int* __restrict__ binned) {
    __shared__ int hist[N_BUCKETS];
    __shared__ int lbase[N_BUCKETS];
    const int t = threadIdx.x;
    for (int i = t; i < N_BUCKETS; i += 256) {
        int h = bhist[blockIdx.x * N_BUCKETS + i];
        lbase[i] = h ? atomicAdd(&bcursor[i], h) : 0;
        hist[i] = 0;   // local rank cursor
    }
    __syncthreads();
    const int e0 = blockIdx.x * EDGES_PER_BLOCK;
    for (int j = t; j < EDGES_PER_BLOCK; j += 256) {
        int c = col[e0 + j];
        int r = row[e0 + j];
        int b = c >> BUCKET_SHIFT;
        int rank = atomicAdd(&hist[b], 1);
        binned[lbase[b] + rank] = ((c & (BUCKET_W - 1)) << 17) | r;
    }
}

// --- 4. bucket-local counting sort -> CSR + row_start + dinv (no global atomics) ---
__global__ __launch_bounds__(256) void bucket_csr_kernel(const int* __restrict__ binned,
                                                         const int* __restrict__ bstart,
                                                         int* __restrict__ csr_src,
                                                         int* __restrict__ row_start,
                                                         float* __restrict__ dinv) {
    __shared__ int hist[BUCKET_W];
    __shared__ int cursor[BUCKET_W];
    const int b = blockIdx.x;
    const int t = threadIdx.x;
    if (t < BUCKET_W) hist[t] = 0;
    __syncthreads();
    const int s = bstart[b], e = bstart[b + 1];
    for (int i = s + t; i < e; i += 256)
        atomicAdd(&hist[binned[i] >> 17], 1);
    __syncthreads();
    if (t < BUCKET_W) cursor[t] = hist[t];
    for (int off = 1; off < BUCKET_W; off <<= 1) {
        __syncthreads();
        int add = (t >= off && t < BUCKET_W) ? cursor[t - off] : 0;
        __syncthreads();
        if (t < BUCKET_W) cursor[t] += add;
    }
    __syncthreads();
    int excl = (t < BUCKET_W) ? (cursor[t] - hist[t]) : 0;
    __syncthreads();
    if (t < BUCKET_W) cursor[t] = excl;
    const int node = b * BUCKET_W + t;
    if (t < BUCKET_W && node < N_NODES) {
        row_start[node] = s + excl;
        dinv[node] = rsqrtf(1.0f + (float)hist[t]);
    }
    __syncthreads();
    for (int i = s + t; i < e; i += 256) {
        int p = binned[i];
        int pos = atomicAdd(&cursor[p >> 17], 1);
        csr_src[s + pos] = p & 0x1FFFF;
    }
}

// --- 5. MFMA gemm: h_s(f16) = dinv[n] * (x @ W1) ---
__global__ __launch_bounds__(256) void gemm_mfma_kernel(const float* __restrict__ x,
                                                        const float* __restrict__ W,
                                                        const float* __restrict__ dinv,
                                                        ushort* __restrict__ h_s) {
    __shared__ ushort xb[16 * 136];
    const int t = threadIdx.x;
    const int l = t & 63;
    const int wv = t >> 6;
    const int q = l >> 4;       // quad
    const int m = l & 15;
    bf16x8 bf[4];               // B[k=32s+8q+j][n=16wv+m]
    {
        const int n = wv * 16 + m;
        #pragma unroll
        for (int s = 0; s < 4; ++s)
            #pragma unroll
            for (int j = 0; j < 8; ++j)
                bf[s][j] = (short)f2bf(W[(32 * s + 8 * q + j) * D_HID + n]);
    }
    for (int tile = 0; tile < GT; ++tile) {
        const int node0 = blockIdx.x * (16 * GT) + tile * 16;
        __syncthreads();
        for (int i = t; i < 512; i += 256) {             // 16 rows x 32 float4
            int r = i >> 5, c4 = i & 31;
            float4 v = *(const float4*)&x[(size_t)(node0 + r) * D_IN + c4 * 4];
            ushort4 u = make_ushort4(f2bf(v.x), f2bf(v.y), f2bf(v.z), f2bf(v.w));
            *(ushort4*)&xb[r * 136 + c4 * 4] = u;
        }
        __syncthreads();
        f32x4 acc = {0.f, 0.f, 0.f, 0.f};
        #pragma unroll
        for (int s = 0; s < 4; ++s) {
            bf16x8 af = *(const bf16x8*)&xb[m * 136 + 32 * s + 8 * q];
            acc = __builtin_amdgcn_mfma_f32_16x16x32_bf16(af, bf[s], acc, 0, 0, 0);
        }
        #pragma unroll
        for (int r = 0; r < 4; ++r) {
            int node = node0 + q * 4 + r;    // C/D: row=(lane>>4)*4+reg, col=lane&15
            _Float16 hv = (_Float16)(acc[r] * dinv[node]);
            h_s[node * D_HID + wv * 16 + m] = __builtin_bit_cast(unsigned short, hv);
        }
    }
}

// --- 6. fused aggregate + bias/BN/relu + fc projection (octet scheme) ---
// wave per node; lane = (edge slot g = lane>>3, feature octet sub = lane&7);
// each gather instr fetches 8 edges (16 B/lane) -> 8-16 lines in flight per wave
__global__ __launch_bounds__(256) void aggregate_kernel(const ushort* __restrict__ h_s,
                                                        const float* __restrict__ dinv,
                                                        const int* __restrict__ row_start,
                                                        const int* __restrict__ csr_src,
                                                        const float* __restrict__ b1,
                                                        const float* __restrict__ gamma,
                                                        const float* __restrict__ beta,
                                                        const float* __restrict__ mean,
                                                        const float* __restrict__ var,
                                                        const float* __restrict__ Wfc,
                                                        float4* __restrict__ uv) {
    const f16x8* __restrict__ hsv = (const f16x8*)h_s;   // [node][8] octets
    const int n = (blockIdx.x * 256 + threadIdx.x) >> 6; // node (grid exact)
    const int lane = threadIdx.x & 63;
    const int g = lane >> 3;                             // edge slot 0..7
    const int sub = lane & 7;                            // feature octet 0..7
    const int start = row_start[n];
    const int cnt = row_start[n + 1] - start;
    f16x8 acc = {(_Float16)0, (_Float16)0, (_Float16)0, (_Float16)0,
                 (_Float16)0, (_Float16)0, (_Float16)0, (_Float16)0};
    if (g == 0) acc = hsv[n * 8 + sub];                  // self-loop (pre-scaled)
    int j = 0;
    for (; j + 16 <= cnt; j += 16) {                     // 16 edges: 2 gathers in flight
        int i0 = csr_src[start + j + g];
        int i1 = csr_src[start + j + 8 + g];
        f16x8 v0 = hsv[i0 * 8 + sub];
        f16x8 v1 = hsv[i1 * 8 + sub];
        acc += v0;
        acc += v1;
    }
    for (; j < cnt; j += 8) {                            // predicated tail, 8 at a time
        int jj = j + g;
        int idx = csr_src[start + (jj < cnt ? jj : 0)];
        f16x8 v = hsv[idx * 8 + sub];
        if (jj < cnt) acc += v;
    }
    // fold the 8 edge slots: xor 8, 16, 32
    #pragma unroll
    for (int off = 8; off < 64; off <<= 1) {
        int4v ai = __builtin_bit_cast(int4v, acc);
        int4v bi;
        bi.x = __shfl_xor(ai.x, off, 64);
        bi.y = __shfl_xor(ai.y, off, 64);
        bi.z = __shfl_xor(ai.z, off, 64);
        bi.w = __shfl_xor(ai.w, off, 64);
        acc += __builtin_bit_cast(f16x8, bi);
    }
    // epilogue: every lane handles its 8 features (g-replicas redundant but wave-free)
    const float dn = dinv[n];
    float p0 = 0.f, p1 = 0.f, p2 = 0.f, p3 = 0.f;
    #pragma unroll
    for (int k = 0; k < 8; ++k) {
        int f = sub * 8 + k;
        float v = (float)acc[k] * dn;
        v = fmaxf(v + b1[f], 0.f);
        v = fmaxf((v - mean[f]) * rsqrtf(var[f] + BN_EPS) * gamma[f] + beta[f], 0.f);
        p0 += v * Wfc[2 * f];
        p1 += v * Wfc[2 * f + 1];
        p2 += v * Wfc[128 + 2 * f];
        p3 += v * Wfc[128 + 2 * f + 1];
    }
    #pragma unroll
    for (int off = 1; off < 8; off <<= 1) {
        p0 += __shfl_xor(p0, off, 64);
        p1 += __shfl_xor(p1, off, 64);
        p2 += __shfl_xor(p2, off, 64);
        p3 += __shfl_xor(p3, off, 64);
    }
    if (lane == 0) uv[n] = make_float4(p0, p1, p2, p3);
}

// --- 7. edge head: 2 edges/thread; out = uv[row].xy + uv[col].zw + bfc ---
__global__ __launch_bounds__(256) void edgeout_kernel(const int* __restrict__ row,
                                                      const int* __restrict__ col,
                                                      const float4* __restrict__ uv,
                                                      const float* __restrict__ bfc,
                                                      float2* __restrict__ out) {
    int i = blockIdx.x * 256 + threadIdx.x;          // over N_EDGES/2 (grid exact)
    int e = i * 2;
    int2 rr = *(const int2*)&row[e];
    int2 cc = *(const int2*)&col[e];
    float4 a0 = uv[rr.x];
    float4 b0 = uv[cc.x];
    float4 a1 = uv[rr.y];
    float4 b1 = uv[cc.y];
    float c0 = bfc[0], c1 = bfc[1];
    float4 o = make_float4(a0.x + b0.z + c0, a0.y + b0.w + c1,
                           a1.x + b1.z + c0, a1.y + b1.w + c1);
    *(float4*)&out[e] = o;
}

extern "C" void kernel_launch(void* const* d_in, const int* in_sizes, int n_in,
                              void* d_out, int out_size, void* d_ws, size_t ws_size,
                              hipStream_t stream) {
    const float* x     = (const float*)d_in[0];
    const int*   ei    = (const int*)d_in[1];
    const int*   row   = ei;             // sources
    const int*   col   = ei + N_EDGES;   // targets
    const float* W1    = (const float*)d_in[2];
    const float* b1    = (const float*)d_in[3];
    const float* gamma = (const float*)d_in[4];
    const float* beta  = (const float*)d_in[5];
    const float* mean  = (const float*)d_in[6];
    const float* var   = (const float*)d_in[7];
    const float* Wfc   = (const float*)d_in[8];
    const float* bfc   = (const float*)d_in[9];
    float2* out = (float2*)d_out;

    char* ws = (char*)d_ws;
    size_t off = 0;
    ushort* h_s      = (ushort*)(ws + off); off += (size_t)N_NODES * D_HID * 2; // 12.8 MB
    int*   binned    = (int*)(ws + off);    off += (size_t)N_EDGES * 4;         // 6.4 MB
    int*   csr_src   = (int*)(ws + off);    off += (size_t)N_EDGES * 4;         // 6.4 MB
    int*   bhist     = (int*)(ws + off);    off += (size_t)N_BIN_BLOCKS * N_BUCKETS * 4; // 6.25 MB
    int*   bcount    = (int*)(ws + off);    off += (size_t)(N_BUCKETS + 2) * 4;
    int*   bstart    = (int*)(ws + off);    off += (size_t)(N_BUCKETS + 2) * 4;
    int*   bcursor   = (int*)(ws + off);    off += (size_t)(N_BUCKETS + 2) * 4;
    int*   row_start = (int*)(ws + off);    off += (size_t)(N_NODES + 4) * 4;
    float* dinv      = (float*)(ws + off);  off += (size_t)N_NODES * 4;
    float4* uv       = (float4*)(ws + off); off += (size_t)N_NODES * 16;        // 1.6 MB

    hipMemsetAsync(bcount, 0, (N_BUCKETS + 1) * sizeof(int), stream);
    bin_count_kernel<<<N_BIN_BLOCKS, 256, 0, stream>>>(col, bcount, bhist);
    scan_buckets_kernel<<<1, 1024, 0, stream>>>(bcount, bstart, bcursor, row_start);
    bin_scatter_kernel<<<N_BIN_BLOCKS, 256, 0, stream>>>(row, col, bhist, bcursor, binned);
    bucket_csr_kernel<<<N_BUCKETS, 256, 0, stream>>>(binned, bstart, csr_src, row_start, dinv);
    gemm_mfma_kernel<<<N_NODES / (16 * GT), 256, 0, stream>>>(x, W1, dinv, h_s);
    aggregate_kernel<<<(N_NODES * 64) / 256, 256, 0, stream>>>(h_s, dinv, row_start, csr_src,
                                                               b1, gamma, beta, mean, var,
                                                               Wfc, uv);
    edgeout_kernel<<<N_EDGES / 512, 256, 0, stream>>>(row, col, uv, bfc, out);
}

// Round 13
// 243.024 us; speedup vs baseline: 1.4712x; 1.4712x over previous
//
#include <hip/hip_runtime.h>

#define N_NODES 100000
#define N_EDGES 1600000
#define D_IN 128
#define D_HID 64
#define BN_EPS 1e-5f

#define BUCKET_SHIFT 7
#define BUCKET_W 128                                    // nodes per bucket
#define N_BUCKETS ((N_NODES + BUCKET_W - 1) / BUCKET_W) // 782
#define N_BIN_BLOCKS 256
#define EDGES_PER_BLOCK (N_EDGES / N_BIN_BLOCKS)        // 6250 exact
#define GT 2                                            // gemm tiles per block

typedef __attribute__((ext_vector_type(8))) short bf16x8;
typedef __attribute__((ext_vector_type(4))) float f32x4;
typedef __attribute__((ext_vector_type(2))) _Float16 f16x2;

__device__ __forceinline__ ushort f2bf(float f) {       // RTNE fp32 -> bf16
    unsigned u = __float_as_uint(f);
    u += 0x7FFF + ((u >> 16) & 1);
    return (ushort)(u >> 16);
}

// --- 1. per-bucket edge counts; persist per-block histograms ---
__global__ __launch_bounds__(256) void bin_count_kernel(const int* __restrict__ col,
                                                        int* __restrict__ bcount,
                                                        int* __restrict__ bhist) {
    __shared__ int hist[N_BUCKETS];
    const int t = threadIdx.x;
    for (int i = t; i < N_BUCKETS; i += 256) hist[i] = 0;
    __syncthreads();
    const int e0 = blockIdx.x * EDGES_PER_BLOCK;
    for (int j = t; j < EDGES_PER_BLOCK; j += 256)
        atomicAdd(&hist[col[e0 + j] >> BUCKET_SHIFT], 1);
    __syncthreads();
    for (int i = t; i < N_BUCKETS; i += 256) {
        int h = hist[i];
        bhist[blockIdx.x * N_BUCKETS + i] = h;
        if (h) atomicAdd(&bcount[i], h);
    }
}

// --- 2. exclusive scan of bucket counts (single block); init cursor ---
__global__ __launch_bounds__(1024) void scan_buckets_kernel(const int* __restrict__ bcount,
                                                            int* __restrict__ bstart,
                                                            int* __restrict__ bcursor,
                                                            int* __restrict__ row_start) {
    __shared__ int tmp[1024];
    int t = threadIdx.x;
    int val = (t < N_BUCKETS) ? bcount[t] : 0;
    tmp[t] = val;
    for (int off = 1; off < 1024; off <<= 1) {
        __syncthreads();
        int add = (t >= off) ? tmp[t - off] : 0;
        __syncthreads();
        tmp[t] += add;
    }
    __syncthreads();
    if (t < N_BUCKETS) {
        int s = tmp[t] - val;
        bstart[t] = s;
        bcursor[t] = s;
    }
    if (t == N_BUCKETS - 1) {
        bstart[N_BUCKETS] = tmp[t];
        row_start[N_NODES] = tmp[t];   // CSR sentinel
    }
}

// --- 3. scatter edges into bucket-grouped array, packed (cl<<17)|row ---
__global__ __launch_bounds__(256) void bin_scatter_kernel(const int* __restrict__ row,
                                                          const int* __restrict__ col,
                                                          const int* __restrict__ bhist,
                                                          int* __restrict__ bcursor,
                                                          int* __restrict__ binned) {
    __shared__ int hist[N_BUCKETS];
    __shared__ int lbase[N_BUCKETS];
    const int t = threadIdx.x;
    for (int i = t; i < N_BUCKETS; i += 256) {
        int h = bhist[blockIdx.x * N_BUCKETS + i];
        lbase[i] = h ? atomicAdd(&bcursor[i], h) : 0;
        hist[i] = 0;   // local rank cursor
    }
    __syncthreads();
    const int e0 = blockIdx.x * EDGES_PER_BLOCK;
    for (int j = t; j < EDGES_PER_BLOCK; j += 256) {
        int c = col[e0 + j];
        int r = row[e0 + j];
        int b = c >> BUCKET_SHIFT;
        int rank = atomicAdd(&hist[b], 1);
        binned[lbase[b] + rank] = ((c & (BUCKET_W - 1)) << 17) | r;
    }
}

// --- 4. bucket-local counting sort -> CSR + row_start + dinv (no global atomics) ---
__global__ __launch_bounds__(256) void bucket_csr_kernel(const int* __restrict__ binned,
                                                         const int* __restrict__ bstart,
                                                         int* __restrict__ csr_src,
                                                         int* __restrict__ row_start,
                                                         float* __restrict__ dinv) {
    __shared__ int hist[BUCKET_W];
    __shared__ int cursor[BUCKET_W];
    const int b = blockIdx.x;
    const int t = threadIdx.x;
    if (t < BUCKET_W) hist[t] = 0;
    __syncthreads();
    const int s = bstart[b], e = bstart[b + 1];
    for (int i = s + t; i < e; i += 256)
        atomicAdd(&hist[binned[i] >> 17], 1);
    __syncthreads();
    if (t < BUCKET_W) cursor[t] = hist[t];
    for (int off = 1; off < BUCKET_W; off <<= 1) {
        __syncthreads();
        int add = (t >= off && t < BUCKET_W) ? cursor[t - off] : 0;
        __syncthreads();
        if (t < BUCKET_W) cursor[t] += add;
    }
    __syncthreads();
    int excl = (t < BUCKET_W) ? (cursor[t] - hist[t]) : 0;
    __syncthreads();
    if (t < BUCKET_W) cursor[t] = excl;
    const int node = b * BUCKET_W + t;
    if (t < BUCKET_W && node < N_NODES) {
        row_start[node] = s + excl;
        dinv[node] = rsqrtf(1.0f + (float)hist[t]);
    }
    __syncthreads();
    for (int i = s + t; i < e; i += 256) {
        int p = binned[i];
        int pos = atomicAdd(&cursor[p >> 17], 1);
        csr_src[s + pos] = p & 0x1FFFF;
    }
}

// --- 5. MFMA gemm: h_s(f16) = dinv[n] * (x @ W1) ---
__global__ __launch_bounds__(256) void gemm_mfma_kernel(const float* __restrict__ x,
                                                        const float* __restrict__ W,
                                                        const float* __restrict__ dinv,
                                                        ushort* __restrict__ h_s) {
    __shared__ ushort xb[16 * 136];
    const int t = threadIdx.x;
    const int l = t & 63;
    const int wv = t >> 6;
    const int q = l >> 4;       // quad
    const int m = l & 15;
    bf16x8 bf[4];               // B[k=32s+8q+j][n=16wv+m]
    {
        const int n = wv * 16 + m;
        #pragma unroll
        for (int s = 0; s < 4; ++s)
            #pragma unroll
            for (int j = 0; j < 8; ++j)
                bf[s][j] = (short)f2bf(W[(32 * s + 8 * q + j) * D_HID + n]);
    }
    for (int tile = 0; tile < GT; ++tile) {
        const int node0 = blockIdx.x * (16 * GT) + tile * 16;
        __syncthreads();
        for (int i = t; i < 512; i += 256) {             // 16 rows x 32 float4
            int r = i >> 5, c4 = i & 31;
            float4 v = *(const float4*)&x[(size_t)(node0 + r) * D_IN + c4 * 4];
            ushort4 u = make_ushort4(f2bf(v.x), f2bf(v.y), f2bf(v.z), f2bf(v.w));
            *(ushort4*)&xb[r * 136 + c4 * 4] = u;
        }
        __syncthreads();
        f32x4 acc = {0.f, 0.f, 0.f, 0.f};
        #pragma unroll
        for (int s = 0; s < 4; ++s) {
            bf16x8 af = *(const bf16x8*)&xb[m * 136 + 32 * s + 8 * q];
            acc = __builtin_amdgcn_mfma_f32_16x16x32_bf16(af, bf[s], acc, 0, 0, 0);
        }
        #pragma unroll
        for (int r = 0; r < 4; ++r) {
            int node = node0 + q * 4 + r;    // C/D: row=(lane>>4)*4+reg, col=lane&15
            _Float16 hv = (_Float16)(acc[r] * dinv[node]);
            h_s[node * D_HID + wv * 16 + m] = __builtin_bit_cast(unsigned short, hv);
        }
    }
}

// --- 6. fused aggregate + bias/BN/relu + fc projection ---
// wave per node; f16x2 per lane (2 lines/instr, coalesced); 8 gathers in flight
// per half via hoisted index loads (MLP from many instrs, not wide ones — R12 lesson)
__global__ __launch_bounds__(256) void aggregate_kernel(const ushort* __restrict__ h_s,
                                                        const float* __restrict__ dinv,
                                                        const int* __restrict__ row_start,
                                                        const int* __restrict__ csr_src,
                                                        const float* __restrict__ b1,
                                                        const float* __restrict__ gamma,
                                                        const float* __restrict__ beta,
                                                        const float* __restrict__ mean,
                                                        const float* __restrict__ var,
                                                        const float* __restrict__ Wfc,
                                                        float4* __restrict__ uv) {
    const f16x2* __restrict__ hsv = (const f16x2*)h_s;   // [node][32] pairs
    const int n = (blockIdx.x * 256 + threadIdx.x) >> 6; // node (grid exact)
    const int lane = threadIdx.x & 63;
    const int half = lane >> 5;
    const int li = lane & 31;                            // feature pair 0..31
    f16x2 acc;
    if (half == 0) acc = hsv[n * 32 + li];               // self-loop (pre-scaled)
    else { acc.x = (_Float16)0; acc.y = (_Float16)0; }
    const int start = row_start[n];
    const int cnt = row_start[n + 1] - start;
    int j = 0;
    for (; j + 16 <= cnt; j += 16) {                     // 16 edges: 8 gathers in flight/half
        int i0 = csr_src[start + j + half];
        int i1 = csr_src[start + j + 2 + half];
        int i2 = csr_src[start + j + 4 + half];
        int i3 = csr_src[start + j + 6 + half];
        int i4 = csr_src[start + j + 8 + half];
        int i5 = csr_src[start + j + 10 + half];
        int i6 = csr_src[start + j + 12 + half];
        int i7 = csr_src[start + j + 14 + half];
        f16x2 v0 = hsv[i0 * 32 + li];
        f16x2 v1 = hsv[i1 * 32 + li];
        f16x2 v2 = hsv[i2 * 32 + li];
        f16x2 v3 = hsv[i3 * 32 + li];
        f16x2 v4 = hsv[i4 * 32 + li];
        f16x2 v5 = hsv[i5 * 32 + li];
        f16x2 v6 = hsv[i6 * 32 + li];
        f16x2 v7 = hsv[i7 * 32 + li];
        acc += v0; acc += v1; acc += v2; acc += v3;
        acc += v4; acc += v5; acc += v6; acc += v7;
    }
    for (; j + 4 <= cnt; j += 4) {                       // 4 edges: 2 per half
        int rA = csr_src[start + j + half];
        int rB = csr_src[start + j + 2 + half];
        f16x2 a = hsv[rA * 32 + li];
        f16x2 b = hsv[rB * 32 + li];
        acc += a;
        acc += b;
    }
    for (; j + 2 <= cnt; j += 2)
        acc += hsv[csr_src[start + j + half] * 32 + li];
    if (j + half < cnt)
        acc += hsv[csr_src[start + j + half] * 32 + li];
    // fold halves
    {
        int ai = __builtin_bit_cast(int, acc);
        int bi = __shfl_xor(ai, 32, 64);
        acc += __builtin_bit_cast(f16x2, bi);
    }
    const float dn = dinv[n];
    float v0 = (float)acc.x * dn;
    float v1 = (float)acc.y * dn;
    float2 bb = *(const float2*)&b1[2 * li];
    float2 mu = *(const float2*)&mean[2 * li];
    float2 vr = *(const float2*)&var[2 * li];
    float2 gm = *(const float2*)&gamma[2 * li];
    float2 bt = *(const float2*)&beta[2 * li];
    v0 = fmaxf(v0 + bb.x, 0.f);
    v1 = fmaxf(v1 + bb.y, 0.f);
    v0 = fmaxf((v0 - mu.x) * rsqrtf(vr.x + BN_EPS) * gm.x + bt.x, 0.f);
    v1 = fmaxf((v1 - mu.y) * rsqrtf(vr.y + BN_EPS) * gm.y + bt.y, 0.f);
    float4 wt = *(const float4*)&Wfc[4 * li];            // rows 2li, 2li+1
    float4 wb = *(const float4*)&Wfc[128 + 4 * li];      // rows 64+2li, 64+2li+1
    float p0 = v0 * wt.x + v1 * wt.z;
    float p1 = v0 * wt.y + v1 * wt.w;
    float p2 = v0 * wb.x + v1 * wb.z;
    float p3 = v0 * wb.y + v1 * wb.w;
    #pragma unroll
    for (int off = 16; off > 0; off >>= 1) {
        p0 += __shfl_xor(p0, off, 64);
        p1 += __shfl_xor(p1, off, 64);
        p2 += __shfl_xor(p2, off, 64);
        p3 += __shfl_xor(p3, off, 64);
    }
    if (lane == 0) uv[n] = make_float4(p0, p1, p2, p3);
}

// --- 7. edge head: 2 edges/thread; out = uv[row].xy + uv[col].zw + bfc ---
__global__ __launch_bounds__(256) void edgeout_kernel(const int* __restrict__ row,
                                                      const int* __restrict__ col,
                                                      const float4* __restrict__ uv,
                                                      const float* __restrict__ bfc,
                                                      float2* __restrict__ out) {
    int i = blockIdx.x * 256 + threadIdx.x;          // over N_EDGES/2 (grid exact)
    int e = i * 2;
    int2 rr = *(const int2*)&row[e];
    int2 cc = *(const int2*)&col[e];
    float4 a0 = uv[rr.x];
    float4 b0 = uv[cc.x];
    float4 a1 = uv[rr.y];
    float4 b1 = uv[cc.y];
    float c0 = bfc[0], c1 = bfc[1];
    float4 o = make_float4(a0.x + b0.z + c0, a0.y + b0.w + c1,
                           a1.x + b1.z + c0, a1.y + b1.w + c1);
    *(float4*)&out[e] = o;
}

extern "C" void kernel_launch(void* const* d_in, const int* in_sizes, int n_in,
                              void* d_out, int out_size, void* d_ws, size_t ws_size,
                              hipStream_t stream) {
    const float* x     = (const float*)d_in[0];
    const int*   ei    = (const int*)d_in[1];
    const int*   row   = ei;             // sources
    const int*   col   = ei + N_EDGES;   // targets
    const float* W1    = (const float*)d_in[2];
    const float* b1    = (const float*)d_in[3];
    const float* gamma = (const float*)d_in[4];
    const float* beta  = (const float*)d_in[5];
    const float* mean  = (const float*)d_in[6];
    const float* var   = (const float*)d_in[7];
    const float* Wfc   = (const float*)d_in[8];
    const float* bfc   = (const float*)d_in[9];
    float2* out = (float2*)d_out;

    char* ws = (char*)d_ws;
    size_t off = 0;
    ushort* h_s      = (ushort*)(ws + off); off += (size_t)N_NODES * D_HID * 2; // 12.8 MB
    int*   binned    = (int*)(ws + off);    off += (size_t)N_EDGES * 4;         // 6.4 MB
    int*   csr_src   = (int*)(ws + off);    off += (size_t)N_EDGES * 4;         // 6.4 MB
    int*   bhist     = (int*)(ws + off);    off += (size_t)N_BIN_BLOCKS * N_BUCKETS * 4; // 0.8 MB
    int*   bcount    = (int*)(ws + off);    off += (size_t)(N_BUCKETS + 2) * 4;
    int*   bstart    = (int*)(ws + off);    off += (size_t)(N_BUCKETS + 2) * 4;
    int*   bcursor   = (int*)(ws + off);    off += (size_t)(N_BUCKETS + 2) * 4;
    int*   row_start = (int*)(ws + off);    off += (size_t)(N_NODES + 4) * 4;
    float* dinv      = (float*)(ws + off);  off += (size_t)N_NODES * 4;
    float4* uv       = (float4*)(ws + off); off += (size_t)N_NODES * 16;        // 1.6 MB

    hipMemsetAsync(bcount, 0, (N_BUCKETS + 1) * sizeof(int), stream);
    bin_count_kernel<<<N_BIN_BLOCKS, 256, 0, stream>>>(col, bcount, bhist);
    scan_buckets_kernel<<<1, 1024, 0, stream>>>(bcount, bstart, bcursor, row_start);
    bin_scatter_kernel<<<N_BIN_BLOCKS, 256, 0, stream>>>(row, col, bhist, bcursor, binned);
    bucket_csr_kernel<<<N_BUCKETS, 256, 0, stream>>>(binned, bstart, csr_src, row_start, dinv);
    gemm_mfma_kernel<<<N_NODES / (16 * GT), 256, 0, stream>>>(x, W1, dinv, h_s);
    aggregate_kernel<<<(N_NODES * 64) / 256, 256, 0, stream>>>(h_s, dinv, row_start, csr_src,
                                                               b1, gamma, beta, mean, var,
                                                               Wfc, uv);
    edgeout_kernel<<<N_EDGES / 512, 256, 0, stream>>>(row, col, uv, bfc, out);
}